// Round 12
// baseline (765.935 us; speedup 1.0000x reference)
//
#include <hip/hip_runtime.h>

#define SEQ_LEN 96
#define PRED_LEN 16
#define HIDDEN 64
#define FEAT 7
#define BATCH 512
#define NB 16                      // batches per block
#define TL (SEQ_LEN + PRED_LEN)    // 112-row sliding timeline
#define XROW 8                     // f16 slots per row (16 B)
#define XBS (113 * XROW)           // per-batch stride in f16 (113 rows: bank de-alias)

typedef _Float16 v8h __attribute__((ext_vector_type(8)));
typedef _Float16 v4h __attribute__((ext_vector_type(4)));
typedef float    v4f __attribute__((ext_vector_type(4)));

#define L2E 1.4426950408889634f

__device__ __forceinline__ float sigm(float v) {
    return __builtin_amdgcn_rcpf(1.0f + __builtin_amdgcn_exp2f(v * (-L2E)));
}
__device__ __forceinline__ float tanh_(float v) {
    return fmaf(2.0f, __builtin_amdgcn_rcpf(
               1.0f + __builtin_amdgcn_exp2f(v * (-2.0f * L2E))), -1.0f);
}

// MFMA formulation: 32 blocks x 256 thr x NB=16 batches. Per step the gate
// pre-activations for all 16 batches are ONE augmented-K GEMM:
//   gates[256 x 16] = W_aug[256 x 96] * v[96 x 16],  v = [h(64); x(7); 1; 0..]
// done as 16 gate-tiles of 16x16x32_f16 MFMA, 3 K-chunks each. Wave w owns
// tiles {w, w+4, w+8, w+12} = units [16w,16w+16) x all 4 gate types, so the
// cell update is IN-LANE (D: col=batch=lane&15, row-unit=(lane>>4)*4+r, m89).
// h re-enters B-layout (B: col=batch=lane&15, k=(lane>>4)*8+j) via an LDS
// buffer ordered [kgroup][batch][8] -> the B read is lane*16B, conflict-free;
// the epilogue's 4 consecutive h per lane = one b64 write. K-augmentation:
// B slot k=71 is constant 1.0 (bias rides in A col 71); A cols 72..95 are
// zero so the B-frag there can hold garbage. One barrier/step, parity ping-pong.
__global__ __launch_bounds__(256)
void lstm_ar_kernel(
    const float* __restrict__ x,     // [B, 96, 7]
    const float* __restrict__ W_ih,  // [256, 7]
    const float* __restrict__ W_hh,  // [256, 64]
    const float* __restrict__ b_ih,  // [256]
    const float* __restrict__ b_hh,  // [256]
    const float* __restrict__ fc_W,  // [7, 64]
    const float* __restrict__ fc_b,  // [7]
    float* __restrict__ out)         // [B, 16, 7]
{
    __shared__ __align__(16) _Float16 xs[NB * XBS];        // ~28.3 KB timelines
    __shared__ __align__(16) _Float16 hbuf[2][8 * NB * 8]; // [parity][kg][n][8]
    __shared__ float fcw[FEAT * HIDDEN];
    __shared__ float fcb[FEAT];

    const int tid  = threadIdx.x;
    const int w    = tid >> 6;        // wave 0..3 -> units [16w, 16w+16)
    const int lane = tid & 63;
    const int q    = lane >> 4;       // quad group 0..3
    const int n    = lane & 15;       // batch column
    const int b0   = blockIdx.x * NB;

    // ---- A-frags (weights, f16, registers): A[m=lane&15][k=q*8+j] ----
    v8h A[4][3];
    #pragma unroll
    for (int g = 0; g < 4; ++g) {
        const int row = (g << 6) + (w << 4) + n;   // gate row in [0,256)
        #pragma unroll
        for (int c = 0; c < 2; ++c) {
            v8h a;
            #pragma unroll
            for (int j = 0; j < 8; ++j)
                a[j] = (_Float16)W_hh[row * HIDDEN + 32 * c + q * 8 + j];
            A[g][c] = a;
        }
        v8h a2;
        #pragma unroll
        for (int j = 0; j < 8; ++j) {
            float v = 0.0f;
            if (q == 0) v = (j < FEAT) ? W_ih[row * FEAT + j]
                                       : (b_ih[row] + b_hh[row]);  // k=71: bias
            a2[j] = (_Float16)v;
        }
        A[g][2] = a2;
    }

    // ---- stage timelines (slot7 = 1.0 for the bias trick), hbuf=0, fc ----
    for (int i = tid; i < NB * TL * XROW; i += 256) {
        int nn  = i / (TL * XROW);
        int rem = i - nn * (TL * XROW);
        int row = rem >> 3, sl = rem & 7;
        float v;
        if (sl == 7)                            v = 1.0f;
        else if (row < SEQ_LEN && sl < FEAT)    v = x[(b0 + nn) * SEQ_LEN * FEAT + row * FEAT + sl];
        else                                    v = 0.0f;
        xs[nn * XBS + row * XROW + sl] = (_Float16)v;
    }
    for (int i = tid; i < 2 * 8 * NB * 8; i += 256) (&hbuf[0][0])[i] = (_Float16)0.0f;
    for (int i = tid; i < FEAT * HIDDEN; i += 256) fcw[i] = fc_W[i];
    if (tid < FEAT) fcb[tid] = fc_b[tid];
    v4f c4 = {0.0f, 0.0f, 0.0f, 0.0f};     // cell states of this lane's 4 units
    __syncthreads();

    // epilogue h-write slot: units 16w + q*4 + r -> kgroup 2w+(q>>1), off (q&1)*4
    const int hwr = (2 * w + (q >> 1)) * 128 + n * 8 + (q & 1) * 4;

    int p = 0;
    for (int k = 0; k < PRED_LEN; ++k) {
        for (int t = 0; t < SEQ_LEN; ++t) {
            const int row = k + t;
            const v8h* hb = (const v8h*)hbuf[p];
            v8h B0 = hb[lane];                 // k = 0..31   (kg = q)
            v8h B1 = hb[64 + lane];            // k = 32..63  (kg = 4+q)
            v8h BX = *(const v8h*)&xs[n * XBS + row * XROW];  // k=64..71 (+garbage, A=0)

            v4f z = {0.0f, 0.0f, 0.0f, 0.0f};
            v4f acc0 = __builtin_amdgcn_mfma_f32_16x16x32_f16(A[0][0], B0, z, 0, 0, 0);
            v4f acc1 = __builtin_amdgcn_mfma_f32_16x16x32_f16(A[1][0], B0, z, 0, 0, 0);
            v4f acc2 = __builtin_amdgcn_mfma_f32_16x16x32_f16(A[2][0], B0, z, 0, 0, 0);
            v4f acc3 = __builtin_amdgcn_mfma_f32_16x16x32_f16(A[3][0], B0, z, 0, 0, 0);
            acc0 = __builtin_amdgcn_mfma_f32_16x16x32_f16(A[0][1], B1, acc0, 0, 0, 0);
            acc1 = __builtin_amdgcn_mfma_f32_16x16x32_f16(A[1][1], B1, acc1, 0, 0, 0);
            acc2 = __builtin_amdgcn_mfma_f32_16x16x32_f16(A[2][1], B1, acc2, 0, 0, 0);
            acc3 = __builtin_amdgcn_mfma_f32_16x16x32_f16(A[3][1], B1, acc3, 0, 0, 0);
            acc0 = __builtin_amdgcn_mfma_f32_16x16x32_f16(A[0][2], BX, acc0, 0, 0, 0);
            acc1 = __builtin_amdgcn_mfma_f32_16x16x32_f16(A[1][2], BX, acc1, 0, 0, 0);
            acc2 = __builtin_amdgcn_mfma_f32_16x16x32_f16(A[2][2], BX, acc2, 0, 0, 0);
            acc3 = __builtin_amdgcn_mfma_f32_16x16x32_f16(A[3][2], BX, acc3, 0, 0, 0);

            // in-lane cell update for 4 units (i,f,g,o = acc0..acc3)
            v4h hh;
            #pragma unroll
            for (int r = 0; r < 4; ++r) {
                float gi = sigm(acc0[r]);
                float gf = sigm(acc1[r]);
                float gg = tanh_(acc2[r]);
                float go = sigm(acc3[r]);
                c4[r] = fmaf(gf, c4[r], gi * gg);
                hh[r] = (_Float16)(go * tanh_(c4[r]));
            }
            *(v4h*)&hbuf[p ^ 1][hwr] = hh;     // one b64, B-layout-ready
            p ^= 1;
            __syncthreads();                   // the ONLY barrier per step
        }
        // after 96 steps (even) latest h is in hbuf[0], p == 0

        // ---- prediction head: thread (n'=tid>>4, f=tid&15<7) ----
        {
            const int nn = tid >> 4, f = tid & 15;
            if (f < FEAT) {
                const v8h* h0 = (const v8h*)hbuf[0];
                float s0 = fcb[f], s1 = 0.0f, s2 = 0.0f, s3 = 0.0f;
                #pragma unroll
                for (int kg = 0; kg < 8; ++kg) {
                    v8h hv = h0[kg * 16 + nn];
                    s0 = fmaf(fcw[f * HIDDEN + kg * 8 + 0], (float)hv[0], s0);
                    s1 = fmaf(fcw[f * HIDDEN + kg * 8 + 1], (float)hv[1], s1);
                    s2 = fmaf(fcw[f * HIDDEN + kg * 8 + 2], (float)hv[2], s2);
                    s3 = fmaf(fcw[f * HIDDEN + kg * 8 + 3], (float)hv[3], s3);
                    s0 = fmaf(fcw[f * HIDDEN + kg * 8 + 4], (float)hv[4], s0);
                    s1 = fmaf(fcw[f * HIDDEN + kg * 8 + 5], (float)hv[5], s1);
                    s2 = fmaf(fcw[f * HIDDEN + kg * 8 + 6], (float)hv[6], s2);
                    s3 = fmaf(fcw[f * HIDDEN + kg * 8 + 7], (float)hv[7], s3);
                }
                float pred = (s0 + s1) + (s2 + s3);
                out[((b0 + nn) * PRED_LEN + k) * FEAT + f] = pred;
                xs[nn * XBS + (SEQ_LEN + k) * XROW + f] = (_Float16)pred;
            }
        }
        __syncthreads();                       // appended row visible before use
    }
}

extern "C" void kernel_launch(void* const* d_in, const int* in_sizes, int n_in,
                              void* d_out, int out_size, void* d_ws, size_t ws_size,
                              hipStream_t stream) {
    const float* x    = (const float*)d_in[0];
    const float* W_ih = (const float*)d_in[1];
    const float* W_hh = (const float*)d_in[2];
    const float* b_ih = (const float*)d_in[3];
    const float* b_hh = (const float*)d_in[4];
    const float* fc_W = (const float*)d_in[5];
    const float* fc_b = (const float*)d_in[6];
    float* out = (float*)d_out;

    lstm_ar_kernel<<<BATCH / NB, 256, 0, stream>>>(x, W_ih, W_hh, b_ih, b_hh, fc_W, fc_b, out);
}

// Round 13
// 572.259 us; speedup vs baseline: 1.3384x; 1.3384x over previous
//
#include <hip/hip_runtime.h>

#define SEQ_LEN 96
#define PRED_LEN 16
#define HIDDEN 64
#define FEAT 7
#define BATCH 512
#define TL (SEQ_LEN + PRED_LEN)   // 112-row xg timeline

typedef float    v2f __attribute__((ext_vector_type(2)));
typedef _Float16 v4h __attribute__((ext_vector_type(4)));

#define L2E 1.4426950408889634f

// DPP pair-swap (0<->1, 2<->3, ...): quad_perm [1,0,3,2]. Pure VALU.
__device__ __forceinline__ float qp_xor1(float v) {
    return __int_as_float(__builtin_amdgcn_mov_dpp(__float_as_int(v), 0xB1, 0xF, 0xF, true));
}

// r9 structure (best: 539us / 843 cyc/step) with the x-path REMOVED from the
// serial chain: at the start of outer-k all 96 window rows are known, so
// xg[row] = 0.5*(W_ih x_row + bias) is precomputed (96 rows at init, appended
// row in each epilogue) and stored f16 as [row][unit][4 gates]. The step
// consumes one prefetched b64 + 4 cvt/add folded BEFORE the pair-reduce (the
// 0.5 scaling is undone by the reduce's doubling -- no predication). r12
// lesson: wall time = 1536 x step critical path; MFMA/batching don't help.
// Block = 128 thr (2 waves) = ONE batch; grid 512 -> 2 blocks/CU staggered
// (r8 lesson), 1 wave/SIMD (r6 lesson). Thread (u=tid>>1, s=tid&1): all 4
// gates of unit u, K-half [32s,32s+32). One barrier/step.
__global__ __launch_bounds__(128)
__attribute__((amdgpu_waves_per_eu(1, 1)))
void lstm_ar_kernel(
    const float* __restrict__ x,     // [B, 96, 7]
    const float* __restrict__ W_ih,  // [256, 7]
    const float* __restrict__ W_hh,  // [256, 64]
    const float* __restrict__ b_ih,  // [256]
    const float* __restrict__ b_hh,  // [256]
    const float* __restrict__ fc_W,  // [7, 64]
    const float* __restrict__ fc_b,  // [7]
    float* __restrict__ out)         // [B, 16, 7]
{
    __shared__ __align__(16) _Float16 xg[TL * HIDDEN * 4];  // 56 KB: 0.5*(Wih.x+b)
    __shared__ float hb0[HIDDEN];     // h ping-pong
    __shared__ float hb1[HIDDEN];
    __shared__ float wihs[256 * FEAT];   // 7 KB (epilogue/init xg computation)
    __shared__ float bias256[256];
    __shared__ float fcw[FEAT * HIDDEN];
    __shared__ float fcb[FEAT];
    __shared__ float predbuf[8];
    __shared__ float xtmp[SEQ_LEN * 8];  // 3 KB transient x staging

    const int tid = threadIdx.x;
    const int b   = blockIdx.x;
    const int u   = tid >> 1;         // hidden unit 0..63
    const int s   = tid & 1;          // K-half / activation-role

    // ---- per-thread weights: 4 gates x 32 K-cols as 16 v2f each ----
    v2f wh[4][16];
    #pragma unroll
    for (int g = 0; g < 4; ++g) {
        const float* wr = W_hh + (u + (g << 6)) * HIDDEN + (s << 5);
        #pragma unroll
        for (int j = 0; j < 16; ++j) wh[g][j] = *(const v2f*)(wr + 2 * j);
    }

    // act_b per-lane consts: s=0 -> gate o (sigmoid), s=1 -> gate g (tanh)
    const float bk  = (s == 1) ? (-2.0f * L2E) : (-L2E);
    const float bm  = (s == 1) ? 2.0f : 1.0f;
    const float bbc = (s == 1) ? -1.0f : 0.0f;

    // ---- stage ----
    for (int i = tid; i < SEQ_LEN * 8; i += 128) {
        int row = i >> 3, f = i & 7;
        xtmp[i] = (f < FEAT) ? x[b * SEQ_LEN * FEAT + row * FEAT + f] : 0.0f;
    }
    for (int i = tid; i < 256 * FEAT; i += 128) wihs[i] = W_ih[i];
    for (int i = tid; i < 256; i += 128) bias256[i] = b_ih[i] + b_hh[i];
    for (int i = tid; i < FEAT * HIDDEN; i += 128) fcw[i] = fc_W[i];
    if (tid < FEAT)   fcb[tid] = fc_b[tid];
    if (tid < HIDDEN) hb0[tid] = 0.0f;
    __syncthreads();

    // ---- precompute xg for the 96 original rows (off the serial chain) ----
    #pragma unroll
    for (int e = 0; e < 2; ++e) {
        const int grow = tid + (e << 7);          // gate row 0..255
        const int uu = grow & 63, gg = grow >> 6;
        float w0 = wihs[grow * FEAT + 0], w1 = wihs[grow * FEAT + 1];
        float w2 = wihs[grow * FEAT + 2], w3 = wihs[grow * FEAT + 3];
        float w4 = wihs[grow * FEAT + 4], w5 = wihs[grow * FEAT + 5];
        float w6 = wihs[grow * FEAT + 6];
        const float bb = bias256[grow];
        for (int row = 0; row < SEQ_LEN; ++row) {
            float4 xa = *(const float4*)&xtmp[row * 8];
            float4 xbv = *(const float4*)&xtmp[row * 8 + 4];
            float acc = bb;
            acc = fmaf(w0, xa.x, acc);
            acc = fmaf(w1, xa.y, acc);
            acc = fmaf(w2, xa.z, acc);
            acc = fmaf(w3, xa.w, acc);
            acc = fmaf(w4, xbv.x, acc);
            acc = fmaf(w5, xbv.y, acc);
            acc = fmaf(w6, xbv.z, acc);
            xg[(row * HIDDEN + uu) * 4 + gg] = (_Float16)(0.5f * acc);
        }
    }
    __syncthreads();

    float c = 0.0f;                   // c_u replica (identical in both pair lanes)

    // One step: consumes prefetched xgv (4 f16: this unit's i,f,g,o x-proj),
    // reads hr, writes hw, prefetches xg row `nrow` before the barrier.
    auto step = [&](v4h xgv, int nrow,
                    const float* __restrict__ hr, float* __restrict__ hw) -> v4h {
        const float4* h4 = (const float4*)(hr + (s << 5));

        v2f A0 = {0.0f, 0.0f}, A1 = A0, A2 = A0, A3 = A0;
        #pragma unroll
        for (int j = 0; j < 8; ++j) {
            float4 hv = h4[j];
            v2f hlo; hlo.x = hv.x; hlo.y = hv.y;
            v2f hhi; hhi.x = hv.z; hhi.y = hv.w;
            A0 = __builtin_elementwise_fma(wh[0][2*j],   hlo, A0);
            A1 = __builtin_elementwise_fma(wh[1][2*j],   hlo, A1);
            A2 = __builtin_elementwise_fma(wh[2][2*j],   hlo, A2);
            A3 = __builtin_elementwise_fma(wh[3][2*j],   hlo, A3);
            A0 = __builtin_elementwise_fma(wh[0][2*j+1], hhi, A0);
            A1 = __builtin_elementwise_fma(wh[1][2*j+1], hhi, A1);
            A2 = __builtin_elementwise_fma(wh[2][2*j+1], hhi, A2);
            A3 = __builtin_elementwise_fma(wh[3][2*j+1], hhi, A3);
        }

        // horizontal + half-xg (cvt hidden under the dot) + ONE pair-reduce:
        // reduce doubles the 0.5*xg back to full value in both lanes.
        float r0 = (A0.x + A0.y) + (float)xgv[0];
        float r1 = (A1.x + A1.y) + (float)xgv[1];
        float r2 = (A2.x + A2.y) + (float)xgv[2];
        float r3 = (A3.x + A3.y) + (float)xgv[3];
        r0 += qp_xor1(r0); r1 += qp_xor1(r1);
        r2 += qp_xor1(r2); r3 += qp_xor1(r3);

        // lane roles: s=0 activates f(r1),o(r3); s=1 activates i(r0),g(r2)
        float aa = s ? r0 : r1;                       // sigmoid in both lanes
        float ab = s ? r2 : r3;                       // tanh | sigmoid
        float ea = __builtin_amdgcn_exp2f(aa * (-L2E));
        float va = __builtin_amdgcn_rcpf(1.0f + ea);  // sigmoid(aa)
        float eb = __builtin_amdgcn_exp2f(ab * bk);
        float rb = __builtin_amdgcn_rcpf(1.0f + eb);
        float vb = fmaf(bm, rb, bbc);

        // exchange with partner lane, canonicalize (i,f,g,o)
        float pa = qp_xor1(va);
        float pb = qp_xor1(vb);
        float gi = s ? va : pa;
        float gf = s ? pa : va;
        float gg = s ? vb : pb;
        float go = s ? pb : vb;

        c = fmaf(gf, c, gi * gg);
        float e2 = __builtin_amdgcn_exp2f(c * (-2.0f * L2E));
        float rr = __builtin_amdgcn_rcpf(1.0f + e2);
        float th = fmaf(2.0f, rr, -1.0f);             // tanh(c)
        float h  = go * th;

        hw[u] = h;                  // both pair lanes: same addr, identical bits

        // prefetch next xg row in the barrier shadow (independent of h)
        v4h nxt = *(const v4h*)&xg[(nrow * HIDDEN + u) * 4];
        __syncthreads();            // the ONLY barrier per step
        return nxt;
    };

    for (int k = 0; k < PRED_LEN; ++k) {
        v4h xv = *(const v4h*)&xg[(k * HIDDEN + u) * 4];   // row k (t=0)
        for (int t = 0; t < SEQ_LEN; t += 2) {
            xv = step(xv, k + t + 1, hb0, hb1);
            xv = step(xv, k + t + 2, hb1, hb0);  // t=94 prefetches row k+96 (<=111, discarded)
        }
        // after 96 steps the latest h is in hb0

        // ---- prediction head: lanes 0..6 of wave 0 ----
        if (tid < FEAT) {
            float p0 = fcb[tid], p1 = 0.0f, p2 = 0.0f, p3 = 0.0f;
            const float4* hh = (const float4*)hb0;
            #pragma unroll
            for (int j = 0; j < 16; ++j) {
                float4 hv = hh[j];
                p0 = fmaf(fcw[tid * HIDDEN + 4*j + 0], hv.x, p0);
                p1 = fmaf(fcw[tid * HIDDEN + 4*j + 1], hv.y, p1);
                p2 = fmaf(fcw[tid * HIDDEN + 4*j + 2], hv.z, p2);
                p3 = fmaf(fcw[tid * HIDDEN + 4*j + 3], hv.w, p3);
            }
            float pred = (p0 + p1) + (p2 + p3);
            out[(b * PRED_LEN + k) * FEAT + tid] = pred;
            predbuf[tid] = pred;
        }
        __syncthreads();            // predbuf visible

        // ---- append xg for row 96+k from the prediction ----
        #pragma unroll
        for (int e = 0; e < 2; ++e) {
            const int grow = tid + (e << 7);
            float acc = bias256[grow];
            #pragma unroll
            for (int f = 0; f < FEAT; ++f)
                acc = fmaf(wihs[grow * FEAT + f], predbuf[f], acc);
            xg[((SEQ_LEN + k) * HIDDEN + (grow & 63)) * 4 + (grow >> 6)] =
                (_Float16)(0.5f * acc);
        }
        __syncthreads();            // appended row visible before use
    }
}

extern "C" void kernel_launch(void* const* d_in, const int* in_sizes, int n_in,
                              void* d_out, int out_size, void* d_ws, size_t ws_size,
                              hipStream_t stream) {
    const float* x    = (const float*)d_in[0];
    const float* W_ih = (const float*)d_in[1];
    const float* W_hh = (const float*)d_in[2];
    const float* b_ih = (const float*)d_in[3];
    const float* b_hh = (const float*)d_in[4];
    const float* fc_W = (const float*)d_in[5];
    const float* fc_b = (const float*)d_in[6];
    float* out = (float*)d_out;

    lstm_ar_kernel<<<BATCH, 128, 0, stream>>>(x, W_ih, W_hh, b_ih, b_hh, fc_W, fc_b, out);
}